// Round 2
// baseline (355.599 us; speedup 1.0000x reference)
//
#include <hip/hip_runtime.h>

#define NPIX 16384
#define IMW  128
#define BIGL 0x7FFFFFFF
#define TPB  512

__device__ __forceinline__ int find_root(int* L, int a){
    int p = L[a];
    while(p != a){
        int gp = L[p];
        if(gp != p) L[a] = gp;   // path halving; benign race
        a = p; p = gp;
    }
    return a;
}

// Link-by-index (root hi -> lo). Links strictly decrease => acyclic under
// concurrency; each successful CAS merges exactly two distinct trees.
__device__ __forceinline__ void unite(int* L, int a, int b, int* mergeCnt){
    while(true){
        a = find_root(L, a);
        b = find_root(L, b);
        if(a == b) return;
        int hi = (a > b) ? a : b;
        int lo = (a > b) ? b : a;
        int old = atomicCAS(&L[hi], hi, lo);
        if(old == hi){ atomicAdd(mergeCnt, 1); return; }
        a = old; b = lo;
    }
}

// One block per (ch, region) image. Incremental superlevel-set persistence:
// counting-sort pixels by activation bucket, add buckets t=99..0 into one
// union-find, b0(t) = pixsuf(t) - merges. b1 via Euler histograms.
__global__ __launch_bounds__(TPB) void persist_kernel(const float* __restrict__ prob,
                                                      const int*   __restrict__ sel,
                                                      float*       __restrict__ betti){
    __shared__ int L[NPIX];                     // 64 KB
    __shared__ unsigned short order[NPIX];      // 32 KB
    __shared__ unsigned char karr[NPIX];        // 16 KB
    __shared__ float thr[100];
    __shared__ int hist[100], start_[100], cursor[100], pixsuf[100];
    __shared__ int ehist[100], edgesuf[100], b0arr[100];
    __shared__ int mergeCnt;

    const int tid = threadIdx.x;
    const int bid = blockIdx.x;
    const int ch = bid >> 2, r = bid & 3;

    for(int t = tid; t < 100; t += TPB){ thr[t] = (float)t / 99.0f; hist[t] = 0; ehist[t] = 0; }
    if(tid == 0) mergeCnt = 0;
    __syncthreads();

    const int region = sel[r];
    const float* img = prob + (size_t)(region * 3 + ch) * NPIX;

    // bin each pixel: k = (#thresholds < v) - 1; active at threshold t iff k >= t
    for(int i = tid; i < NPIX; i += TPB){
        float v = img[i];
        int lo = 0, hi = 100;
        #pragma unroll
        for(int s = 0; s < 7; s++){ int mid = (lo + hi) >> 1; if(thr[mid] < v) lo = mid + 1; else hi = mid; }
        int k = lo - 1;
        karr[i] = (unsigned char)(k < 0 ? 255 : k);
        L[i] = BIGL;
        if(k >= 0) atomicAdd(&hist[k], 1);
    }
    __syncthreads();

    if(tid == 0){
        int s = 0;
        for(int t = 99; t >= 0; t--){ start_[t] = s; cursor[t] = s; s += hist[t]; pixsuf[t] = s; }
    }
    __syncthreads();

    // scatter into bucket-descending order + edge activation histogram
    for(int i = tid; i < NPIX; i += TPB){
        int kc = karr[i];
        if(kc != 255){ int pos = atomicAdd(&cursor[kc], 1); order[pos] = (unsigned short)i; }
        int ka = (kc == 255) ? -1 : kc;
        int x = i & (IMW - 1);
        if(x < IMW - 1){
            int kn = karr[i + 1];   int kb = (kn == 255) ? -1 : kn;
            int km = ka < kb ? ka : kb;
            if(km >= 0) atomicAdd(&ehist[km], 1);
        }
        if(i < NPIX - IMW){
            int kn = karr[i + IMW]; int kb = (kn == 255) ? -1 : kn;
            int km = ka < kb ? ka : kb;
            if(km >= 0) atomicAdd(&ehist[km], 1);
        }
    }
    __syncthreads();
    if(tid == 0){
        int es = 0;
        for(int t = 99; t >= 0; t--){ es += ehist[t]; edgesuf[t] = es; }
    }
    __syncthreads();

    // persistence sweep: t = 99 .. 0
    for(int t = 99; t >= 0; t--){
        const int s = start_[t], e = s + hist[t];
        for(int idx = s + tid; idx < e; idx += TPB){ int i = order[idx]; L[i] = i; }
        __syncthreads();
        for(int idx = s + tid; idx < e; idx += TPB){
            int i = order[idx];
            int x = i & (IMW - 1);
            if(x < IMW - 1    && L[i + 1]   != BIGL) unite(L, i, i + 1,   &mergeCnt);
            if(x > 0          && L[i - 1]   != BIGL) unite(L, i, i - 1,   &mergeCnt);
            if(i < NPIX - IMW && L[i + IMW] != BIGL) unite(L, i, i + IMW, &mergeCnt);
            if(i >= IMW       && L[i - IMW] != BIGL) unite(L, i, i - IMW, &mergeCnt);
        }
        __syncthreads();
        if(tid == 0) b0arr[t] = pixsuf[t] - mergeCnt;   // safe: next unions gated by next barrier
    }
    __syncthreads();

    for(int t = tid; t < 100; t += TPB){
        float b0f = (float)b0arr[t];
        float b1f = b0f - (float)(pixsuf[t] - edgesuf[t]);   // b1 = b0 - (pix - edges)
        size_t o = (((size_t)ch * 100 + t) * 4 + r) * 2;
        betti[o]     = b0f;
        betti[o + 1] = b1f;
    }
}

// One block per (region, code-column) row: diff codes across thresholds,
// stable-partition sort (== stable argsort by birth), stable rank-sort of gt
// (staged in LDS), L1 match + unmatched length partial sums.
__global__ __launch_bounds__(128) void rows_kernel(const float* __restrict__ betti,
                                                   const float* __restrict__ gt,
                                                   float*       __restrict__ partials){
    __shared__ float codes[100];
    __shared__ float birth[99], death[99], bs0[99], bs1[99], gs0[99], gs1[99];
    __shared__ float gsh[198];
    __shared__ float red[4];
    const int row = blockIdx.x;          // r*6 + j
    const int r = row / 6, j = row % 6;
    const int chmap[6] = {0, 0, 1, 1, 0, 0};   // inside, boundary, union(=inside)
    const int ch = chmap[j], comp = j & 1;
    const int tid = threadIdx.x;

    if(tid < 100) codes[tid] = betti[(((size_t)ch * 100 + tid) * 4 + r) * 2 + comp];
    const float* g = gt + (size_t)row * 99 * 2;
    for(int i = tid; i < 198; i += 128) gsh[i] = g[i];
    __syncthreads();

    float b = 0.f, d = 0.f;
    if(tid < 99){
        float dv = codes[tid + 1] - codes[tid];
        float th = (float)tid / 99.0f;
        b = (dv > 0.f) ? th : 0.f;
        d = (dv < 0.f) ? th : 0.f;
        birth[tid] = b; death[tid] = d;
    }
    __syncthreads();

    if(tid < 99){
        // stable sort by birth == stable partition (positives already ascending)
        int zb = 0, tz = 0;
        for(int k = 0; k < 99; k++){
            int z = (birth[k] == 0.f) ? 1 : 0;
            tz += z;
            if(k < tid) zb += z;
        }
        int pos = (b == 0.f) ? zb : (tz + tid - zb);
        bs0[pos] = b; bs1[pos] = d;

        float gb = gsh[tid * 2];
        int rank = 0;
        for(int k = 0; k < 99; k++){
            float o = gsh[k * 2];
            rank += (o < gb || (o == gb && k < tid)) ? 1 : 0;
        }
        gs0[rank] = gb; gs1[rank] = gsh[tid * 2 + 1];
    }
    __syncthreads();

    float m = 0.f, u = 0.f;
    if(tid < 99){
        m = fabsf(bs0[tid] - gs0[tid]) + fabsf(bs1[tid] - gs1[tid]);
        u = d - b;
    }
    for(int off = 32; off > 0; off >>= 1){
        m += __shfl_down(m, off, 64);
        u += __shfl_down(u, off, 64);
    }
    if((tid & 63) == 0){ red[(tid >> 6) * 2] = m; red[(tid >> 6) * 2 + 1] = u; }
    __syncthreads();
    if(tid == 0){
        partials[row]      = red[0] + red[2];
        partials[24 + row] = red[1] + red[3];
    }
}

__global__ __launch_bounds__(64) void final_kernel(const float* __restrict__ partials,
                                                   float* __restrict__ out){
    const int tid = threadIdx.x;
    float m = (tid < 24) ? partials[tid]      : 0.f;
    float u = (tid < 24) ? partials[24 + tid] : 0.f;
    for(int off = 32; off > 0; off >>= 1){
        m += __shfl_down(m, off, 64);
        u += __shfl_down(u, off, 64);
    }
    if(tid == 0) out[0] = m / 2376.0f + u / 24.0f;   // mean[4,6,99] + mean[4,6]
}

extern "C" void kernel_launch(void* const* d_in, const int* in_sizes, int n_in,
                              void* d_out, int out_size, void* d_ws, size_t ws_size,
                              hipStream_t stream){
    const float* prob = (const float*)d_in[0];   // [4,3,128,128] f32
    const int*   sel  = (const int*)d_in[1];     // [4] int32 (x64 disabled)
    const float* gt   = (const float*)d_in[2];   // [4,6,99,2] f32
    float* ws       = (float*)d_ws;
    float* betti    = ws;            // [2][100][4][2] = 1600 floats
    float* partials = ws + 1600;     // matched[24] + unmatched[24]

    persist_kernel<<<8, TPB, 0, stream>>>(prob, sel, betti);
    rows_kernel   <<<24, 128, 0, stream>>>(betti, gt, partials);
    final_kernel  <<<1, 64, 0, stream>>>(partials, (float*)d_out);
}

// Round 3
// 105.554 us; speedup vs baseline: 3.3689x; 3.3689x over previous
//
#include <hip/hip_runtime.h>

#define NPIX 16384
#define IMW  128

__device__ __forceinline__ int find_root(int* L, int a){
    int p = L[a];
    while(p != a){
        int gp = L[p];
        if(gp != p) L[a] = gp;   // path halving; benign race
        a = p; p = gp;
    }
    return a;
}

// Link-by-index (root hi -> lo): links strictly decrease => acyclic under
// concurrency. Roots are exactly nodes with L[n]==n after all unions.
__device__ __forceinline__ void unite(int* L, int a, int b){
    while(true){
        a = find_root(L, a);
        b = find_root(L, b);
        if(a == b) return;
        int hi = (a > b) ? a : b;
        int lo = (a > b) ? b : a;
        int old = atomicCAS(&L[hi], hi, lo);
        if(old == hi) return;
        a = old; b = lo;
    }
}

// One block per (ch, threshold, region). Rows as 2x u64 bitmasks (ballot-built).
// pix/edges via popcounts. Union-find over RUNS (node = row*64 + run index),
// one union per vertical contact-segment start. b0 = #roots.
__global__ __launch_bounds__(256) void ccl_kernel(const float* __restrict__ prob,
                                                  const int*   __restrict__ sel,
                                                  float*       __restrict__ betti){
    __shared__ unsigned long long M[256];   // row masks: word w = (row<<1)|half
    __shared__ unsigned long long S[256];   // run-start masks
    __shared__ int L[8192];                 // union-find over run ids (32 KB)
    __shared__ int red[12];
    const int tid = threadIdx.x, bid = blockIdx.x;
    const int ch = bid / 400, t = (bid % 400) >> 2, r = bid & 3;
    const float th = (float)t / 99.0f;
    const float* img = prob + (size_t)(sel[r] * 3 + ch) * NPIX;

    {   // init union-find arena (vectorized)
        int4* L4 = (int4*)L;
        for(int i = tid; i < 2048; i += 256){ int b = i * 4; L4[i] = make_int4(b, b+1, b+2, b+3); }
    }

    // build bitmasks: wave's ballot over 64 consecutive pixels = one u64 word
    const int lane = tid & 63, wave = tid >> 6;
    for(int c = 0; c < 64; c++){
        float v = img[c * 256 + wave * 64 + lane];
        unsigned long long mm = __ballot(v > th);
        if(lane == 0) M[c * 4 + wave] = mm;
    }
    __syncthreads();

    // per-word masks & counts (thread <-> word)
    const int w = tid, row = w >> 1, half = w & 1;
    const unsigned long long m = M[w];
    const unsigned long long lcar = half ? (M[w - 1] >> 63) : 0ULL;
    const unsigned long long s = m & ~((m << 1) | lcar);
    S[w] = s;
    int pix   = __popcll(m);
    int edges = __popcll(m & ((m << 1) | lcar));           // horizontal pairs
    const unsigned long long va = (row > 0) ? M[w - 2] : 0ULL;
    edges += __popcll(m & va);                              // vertical pairs
    __syncthreads();

    const int base = half ? __popcll(S[w - 1]) : 0;         // runs in earlier word of row
    if(row > 0){
        unsigned long long c = m & va;
        const unsigned long long ccar = half ? ((M[w - 1] & M[w - 3]) >> 63) : 0ULL;
        unsigned long long cs = c & ~((c << 1) | ccar);     // contact-segment starts
        const unsigned long long sa = S[w - 2];
        const int basea = half ? __popcll(S[w - 3]) : 0;
        while(cs){
            const int x = __ffsll(cs) - 1;
            cs &= cs - 1;
            const unsigned long long lm = (2ULL << x) - 1;  // bits [0..x]
            const int na = (row - 1) * 64 + basea + __popcll(sa & lm) - 1;
            const int nb =  row      * 64 + base  + __popcll(s  & lm) - 1;
            unite(L, na, nb);
        }
    }
    __syncthreads();

    int b0 = 0;
    {   const int nrun = __popcll(s);
        for(int j = 0; j < nrun; j++){ const int n = row * 64 + base + j; b0 += (L[n] == n); } }

    for(int off = 32; off; off >>= 1){
        pix   += __shfl_down(pix,   off, 64);
        edges += __shfl_down(edges, off, 64);
        b0    += __shfl_down(b0,    off, 64);
    }
    if(lane == 0){ red[wave*3] = pix; red[wave*3+1] = edges; red[wave*3+2] = b0; }
    __syncthreads();
    if(tid == 0){
        int P = 0, E = 0, B = 0;
        for(int k = 0; k < 4; k++){ P += red[k*3]; E += red[k*3+1]; B += red[k*3+2]; }
        const float b0f = (float)B;
        const float b1f = b0f - ((float)P - (float)E);      // b1 = b0 - (pix - edges)
        const size_t o = (((size_t)ch * 100 + t) * 4 + r) * 2;
        betti[o] = b0f; betti[o + 1] = b1f;
    }
}

// One block per (region, code-column) row; accumulates directly into out[0]
// (pre-zeroed via hipMemsetAsync) with a device-scope float atomicAdd.
__global__ __launch_bounds__(128) void rows_kernel(const float* __restrict__ betti,
                                                   const float* __restrict__ gt,
                                                   float*       __restrict__ out){
    __shared__ float codes[100];
    __shared__ float birth[99], bs0[99], bs1[99], gs0[99], gs1[99];
    __shared__ float gsh[198];
    __shared__ float red[4];
    const int row = blockIdx.x;          // r*6 + j
    const int r = row / 6, j = row % 6;
    const int chmap[6] = {0, 0, 1, 1, 0, 0};   // inside, boundary, union(=inside)
    const int ch = chmap[j], comp = j & 1;
    const int tid = threadIdx.x;

    if(tid < 100) codes[tid] = betti[(((size_t)ch * 100 + tid) * 4 + r) * 2 + comp];
    const float* g = gt + (size_t)row * 99 * 2;
    for(int i = tid; i < 198; i += 128) gsh[i] = g[i];
    __syncthreads();

    float b = 0.f, d = 0.f;
    if(tid < 99){
        const float dv = codes[tid + 1] - codes[tid];
        const float thv = (float)tid / 99.0f;
        b = (dv > 0.f) ? thv : 0.f;
        d = (dv < 0.f) ? thv : 0.f;
        birth[tid] = b;
    }
    __syncthreads();

    if(tid < 99){
        // stable sort by birth == stable partition (positive births already ascending)
        int zb = 0, tz = 0;
        for(int k = 0; k < 99; k++){
            const int z = (birth[k] == 0.f) ? 1 : 0;
            tz += z;
            if(k < tid) zb += z;
        }
        const int pos = (b == 0.f) ? zb : (tz + tid - zb);
        bs0[pos] = b; bs1[pos] = d;

        const float gb = gsh[tid * 2];
        int rank = 0;
        for(int k = 0; k < 99; k++){
            const float o = gsh[k * 2];
            rank += (o < gb || (o == gb && k < tid)) ? 1 : 0;
        }
        gs0[rank] = gb; gs1[rank] = gsh[tid * 2 + 1];
    }
    __syncthreads();

    float mm = 0.f, u = 0.f;
    if(tid < 99){
        mm = fabsf(bs0[tid] - gs0[tid]) + fabsf(bs1[tid] - gs1[tid]);
        u = d - b;
    }
    for(int off = 32; off; off >>= 1){
        mm += __shfl_down(mm, off, 64);
        u  += __shfl_down(u,  off, 64);
    }
    if((tid & 63) == 0){ red[(tid >> 6)*2] = mm; red[(tid >> 6)*2 + 1] = u; }
    __syncthreads();
    if(tid == 0)
        atomicAdd(out, (red[0] + red[2]) / 2376.0f + (red[1] + red[3]) / 24.0f);
}

extern "C" void kernel_launch(void* const* d_in, const int* in_sizes, int n_in,
                              void* d_out, int out_size, void* d_ws, size_t ws_size,
                              hipStream_t stream){
    const float* prob = (const float*)d_in[0];   // [4,3,128,128] f32
    const int*   sel  = (const int*)d_in[1];     // [4]
    const float* gt   = (const float*)d_in[2];   // [4,6,99,2] f32
    float* betti = (float*)d_ws;                 // [2][100][4][2] = 1600 floats

    hipMemsetAsync(d_out, 0, sizeof(float), stream);
    ccl_kernel <<<800, 256, 0, stream>>>(prob, sel, betti);
    rows_kernel<<<24, 128, 0, stream>>>(betti, gt, (float*)d_out);
}